// Round 1
// baseline (84.833 us; speedup 1.0000x reference)
//
#include <hip/hip_runtime.h>

#define NROWS 8192
#define DIM 512
#define NVEC4 (DIM / 4)   // 128 float4 per row
#define LMAX 512
#define MAXG 2048          // cap on per-label bucket size (expected ~16, max ~45)

__device__ __forceinline__ float wave_reduce_sum(float v) {
#pragma unroll
    for (int m = 32; m > 0; m >>= 1) v += __shfl_xor(v, m, 64);
    return v;
}

// Dot product of rows ia, ib (raw embeddings), cooperatively across one wave.
// All 64 lanes of the wave must call this (ia/ib wave-uniform).
__device__ __forceinline__ float dot_rows(const float4* __restrict__ E4,
                                          int ia, int ib, int lane) {
    const float4* a = E4 + (size_t)ia * NVEC4;
    const float4* b = E4 + (size_t)ib * NVEC4;
    float4 x = a[lane], y = b[lane];
    float s = x.x * y.x + x.y * y.y + x.z * y.z + x.w * y.w;
    x = a[lane + 64]; y = b[lane + 64];
    s += x.x * y.x + x.y * y.y + x.z * y.z + x.w * y.w;
    return wave_reduce_sum(s);
}

// One wave per row: invn[i] = 1 / max(||E[i]||, 1e-12)
__global__ void invnorm_kernel(const float* __restrict__ E,
                               float* __restrict__ invn, int n) {
    int wave = (blockIdx.x * blockDim.x + threadIdx.x) >> 6;
    int lane = threadIdx.x & 63;
    if (wave >= n) return;
    const float4* a = (const float4*)E + (size_t)wave * NVEC4;
    float4 x = a[lane];
    float s = x.x * x.x + x.y * x.y + x.z * x.z + x.w * x.w;
    x = a[lane + 64];
    s += x.x * x.x + x.y * x.y + x.z * x.z + x.w * x.w;
    s = wave_reduce_sum(s);
    if (lane == 0) invn[wave] = 1.0f / fmaxf(sqrtf(s), 1e-12f);
}

// One block per label. Collect conserved rows with this label, then enumerate
// intra-bucket pairs (a<b) with differing graph ids.
__global__ void pos_kernel(const float* __restrict__ E,
                           const float* __restrict__ invn,
                           const int* __restrict__ labels,
                           const int* __restrict__ graphs,
                           const int* __restrict__ cats,
                           int n, float* __restrict__ sums,
                           unsigned int* __restrict__ cnts) {
    __shared__ int idxs[MAXG];
    __shared__ int gcount;
    __shared__ float bsum;
    __shared__ unsigned int bcnt;
    int tid = threadIdx.x;
    if (tid == 0) { gcount = 0; bsum = 0.0f; bcnt = 0u; }
    __syncthreads();

    int lbl = blockIdx.x;
    for (int i = tid; i < n; i += blockDim.x) {
        if (labels[i] == lbl && cats[i] < 3) {
            int p = atomicAdd(&gcount, 1);
            if (p < MAXG) idxs[p] = i;
        }
    }
    __syncthreads();

    int g = min(gcount, MAXG);
    int npairs = g * (g - 1) / 2;
    int wid = tid >> 6, lane = tid & 63;
    int nw = blockDim.x >> 6;

    for (int p = wid; p < npairs; p += nw) {
        // unrank pair index p -> (a, b), a < b  (g is small, loop is cheap)
        int a = 0, rem = p;
        while (rem >= g - 1 - a) { rem -= g - 1 - a; ++a; }
        int b = a + 1 + rem;
        int ia = idxs[a], ib = idxs[b];
        if (graphs[ia] != graphs[ib]) {
            float d = dot_rows((const float4*)E, ia, ib, lane);
            if (lane == 0) {
                float sim = d * invn[ia] * invn[ib];
                atomicAdd(&bsum, 1.0f - sim);
                atomicAdd(&bcnt, 1u);
            }
        }
    }
    __syncthreads();
    if (tid == 0 && bcnt > 0u) {
        atomicAdd(&sums[0], bsum);
        atomicAdd(&cnts[0], bcnt);
    }
}

// One wave per sampled pair.
__global__ void neg_kernel(const float* __restrict__ E,
                           const float* __restrict__ invn,
                           const int* __restrict__ labels,
                           const int* __restrict__ graphs,
                           const int* __restrict__ cats,
                           const int* __restrict__ idx1,
                           const int* __restrict__ idx2,
                           int S, float* __restrict__ sums,
                           unsigned int* __restrict__ cnts) {
    __shared__ float bsum;
    __shared__ unsigned int bcnt;
    if (threadIdx.x == 0) { bsum = 0.0f; bcnt = 0u; }
    __syncthreads();

    int wid = threadIdx.x >> 6, lane = threadIdx.x & 63;
    int s = blockIdx.x * (blockDim.x >> 6) + wid;
    if (s < S) {
        int i = idx1[s], j = idx2[s];
        if (graphs[i] != graphs[j] && labels[i] != labels[j] &&
            (cats[i] < 3 || cats[j] < 3)) {
            float d = dot_rows((const float4*)E, i, j, lane);
            if (lane == 0) {
                float sim = d * invn[i] * invn[j];
                atomicAdd(&bsum, fmaxf(sim, 0.0f));  // MARGIN = 0
                atomicAdd(&bcnt, 1u);
            }
        }
    }
    __syncthreads();
    if (threadIdx.x == 0 && bcnt > 0u) {
        atomicAdd(&sums[1], bsum);
        atomicAdd(&cnts[1], bcnt);
    }
}

__global__ void finalize_kernel(const float* __restrict__ sums,
                                const unsigned int* __restrict__ cnts,
                                float* __restrict__ out) {
    float pos = (cnts[0] > 0u) ? sums[0] / (float)cnts[0] : 0.0f;
    float neg = (cnts[1] > 0u) ? sums[1] / (float)cnts[1] : 0.0f;
    out[0] = pos + neg;
}

extern "C" void kernel_launch(void* const* d_in, const int* in_sizes, int n_in,
                              void* d_out, int out_size, void* d_ws, size_t ws_size,
                              hipStream_t stream) {
    const float* E      = (const float*)d_in[0];
    const int* labels   = (const int*)d_in[1];
    const int* graphs   = (const int*)d_in[2];
    const int* cats     = (const int*)d_in[3];
    const int* idx1     = (const int*)d_in[4];
    const int* idx2     = (const int*)d_in[5];
    int n = in_sizes[1];   // 8192
    int S = in_sizes[4];   // 5000

    float* invn = (float*)d_ws;
    char* accbase = (char*)d_ws + (size_t)n * sizeof(float);
    float* sums = (float*)accbase;                       // [pos_sum, neg_sum]
    unsigned int* cnts = (unsigned int*)(accbase + 2 * sizeof(float)); // [pos_cnt, neg_cnt]

    hipMemsetAsync(accbase, 0, 4 * sizeof(float), stream);

    // 4 waves (rows) per 256-thread block
    int nb_norm = (n + 3) / 4;
    invnorm_kernel<<<nb_norm, 256, 0, stream>>>(E, invn, n);

    pos_kernel<<<LMAX, 256, 0, stream>>>(E, invn, labels, graphs, cats, n, sums, cnts);

    int nb_neg = (S + 3) / 4;  // 4 pairs per block
    neg_kernel<<<nb_neg, 256, 0, stream>>>(E, invn, labels, graphs, cats,
                                           idx1, idx2, S, sums, cnts);

    finalize_kernel<<<1, 1, 0, stream>>>(sums, cnts, (float*)d_out);
}

// Round 2
// 50.169 us; speedup vs baseline: 1.6910x; 1.6910x over previous
//
#include <hip/hip_runtime.h>

#define DIM 512
#define NVEC4 (DIM / 4)   // 128 float4 per row
#define LMAX 512
#define MAXB 64           // cap on conserved rows per label (expected ~8, max <<64)
#define PAIR_CAP 65536

__device__ __forceinline__ float wave_reduce_sum(float v) {
#pragma unroll
    for (int m = 32; m > 0; m >>= 1) v += __shfl_xor(v, m, 64);
    return v;
}

// Dot of rows ia, ib (raw embeddings), cooperatively across one wave.
__device__ __forceinline__ float dot_rows(const float4* __restrict__ E4,
                                          int ia, int ib, int lane) {
    const float4* a = E4 + (size_t)ia * NVEC4;
    const float4* b = E4 + (size_t)ib * NVEC4;
    float4 x0 = a[lane], y0 = b[lane];
    float4 x1 = a[lane + 64], y1 = b[lane + 64];
    float s = x0.x * y0.x + x0.y * y0.y + x0.z * y0.z + x0.w * y0.w;
    s += x1.x * y1.x + x1.y * y1.y + x1.z * y1.z + x1.w * y1.w;
    return wave_reduce_sum(s);
}

// Zero the small counter region (bcnt[LMAX], paircnt, negcnt, sums[2]).
__global__ void zero_kernel(int* __restrict__ bcnt, int* __restrict__ paircnt,
                            int* __restrict__ negcnt, float* __restrict__ sums) {
    int t = threadIdx.x;
    for (int i = t; i < LMAX; i += blockDim.x) bcnt[i] = 0;
    if (t == 0) { *paircnt = 0; *negcnt = 0; sums[0] = 0.0f; sums[1] = 0.0f; }
}

// One wave per row: invnorm + bucket insert (lane 0).
__global__ void prep_kernel(const float* __restrict__ E,
                            const int* __restrict__ labels,
                            const int* __restrict__ cats,
                            float* __restrict__ invn,
                            int* __restrict__ bcnt,
                            int* __restrict__ blist, int n) {
    int row = (blockIdx.x * blockDim.x + threadIdx.x) >> 6;
    int lane = threadIdx.x & 63;
    if (row >= n) return;
    const float4* a = (const float4*)E + (size_t)row * NVEC4;
    float4 x0 = a[lane], x1 = a[lane + 64];
    float s = x0.x * x0.x + x0.y * x0.y + x0.z * x0.z + x0.w * x0.w;
    s += x1.x * x1.x + x1.y * x1.y + x1.z * x1.z + x1.w * x1.w;
    s = wave_reduce_sum(s);
    if (lane == 0) {
        invn[row] = 1.0f / fmaxf(sqrtf(s), 1e-12f);
        if (cats[row] < 3) {
            int lbl = labels[row];
            int p = atomicAdd(&bcnt[lbl], 1);
            if (p < MAXB) blist[lbl * MAXB + p] = row;
        }
    }
}

// Blocks [0, LMAX): enumerate intra-bucket pairs with diff graph into pairs[].
// Blocks [LMAX, ...): validate negative samples into negp[].
__global__ void pairgen_kernel(const int* __restrict__ labels,
                               const int* __restrict__ graphs,
                               const int* __restrict__ cats,
                               const int* __restrict__ idx1,
                               const int* __restrict__ idx2, int S,
                               const int* __restrict__ bcnt,
                               const int* __restrict__ blist,
                               int* __restrict__ paircnt, int2* __restrict__ pairs,
                               int* __restrict__ negcnt, int2* __restrict__ negp) {
    int b = blockIdx.x;
    if (b < LMAX) {
        int g = min(bcnt[b], MAXB);
        int npairs = g * (g - 1) / 2;
        const int* lst = blist + b * MAXB;
        for (int p = threadIdx.x; p < npairs; p += blockDim.x) {
            int a = 0, rem = p;
            while (rem >= g - 1 - a) { rem -= g - 1 - a; ++a; }
            int bb = a + 1 + rem;
            int ia = lst[a], ib = lst[bb];
            if (graphs[ia] != graphs[ib]) {
                int slot = atomicAdd(paircnt, 1);
                if (slot < PAIR_CAP) pairs[slot] = make_int2(ia, ib);
            }
        }
    } else {
        int s = (b - LMAX) * blockDim.x + threadIdx.x;
        if (s < S) {
            int i = idx1[s], j = idx2[s];
            if (graphs[i] != graphs[j] && labels[i] != labels[j] &&
                (cats[i] < 3 || cats[j] < 3)) {
                int slot = atomicAdd(negcnt, 1);
                negp[slot] = make_int2(i, j);
            }
        }
    }
}

// Waves grid-stride over pos pairs then neg pairs; register accumulate,
// LDS reduce, one global atomic pair per block.
__global__ void dots_kernel(const float* __restrict__ E,
                            const float* __restrict__ invn,
                            const int2* __restrict__ pairs,
                            const int* __restrict__ paircnt,
                            const int2* __restrict__ negp,
                            const int* __restrict__ negcnt,
                            float* __restrict__ sums) {
    __shared__ float s_pos, s_neg;
    if (threadIdx.x == 0) { s_pos = 0.0f; s_neg = 0.0f; }
    __syncthreads();

    int np = min(*paircnt, PAIR_CAP);
    int nn = *negcnt;
    int total = np + nn;
    int wid = threadIdx.x >> 6, lane = threadIdx.x & 63;
    int gw = blockIdx.x * (blockDim.x >> 6) + wid;
    int nwtot = gridDim.x * (blockDim.x >> 6);

    float accp = 0.0f, accn = 0.0f;
    for (int t = gw; t < total; t += nwtot) {
        int2 pr = (t < np) ? pairs[t] : negp[t - np];
        float d = dot_rows((const float4*)E, pr.x, pr.y, lane);
        float sim = d * invn[pr.x] * invn[pr.y];
        if (t < np) accp += 1.0f - sim;
        else        accn += fmaxf(sim, 0.0f);   // MARGIN = 0
    }
    if (lane == 0) {
        if (accp != 0.0f) atomicAdd(&s_pos, accp);
        if (accn != 0.0f) atomicAdd(&s_neg, accn);
    }
    __syncthreads();
    if (threadIdx.x == 0) {
        if (s_pos != 0.0f) atomicAdd(&sums[0], s_pos);
        if (s_neg != 0.0f) atomicAdd(&sums[1], s_neg);
    }
}

__global__ void finalize_kernel(const float* __restrict__ sums,
                                const int* __restrict__ paircnt,
                                const int* __restrict__ negcnt,
                                float* __restrict__ out) {
    int pc = min(*paircnt, PAIR_CAP);
    int nc = *negcnt;
    float pos = (pc > 0) ? sums[0] / (float)pc : 0.0f;
    float neg = (nc > 0) ? sums[1] / (float)nc : 0.0f;
    out[0] = pos + neg;
}

extern "C" void kernel_launch(void* const* d_in, const int* in_sizes, int n_in,
                              void* d_out, int out_size, void* d_ws, size_t ws_size,
                              hipStream_t stream) {
    const float* E    = (const float*)d_in[0];
    const int* labels = (const int*)d_in[1];
    const int* graphs = (const int*)d_in[2];
    const int* cats   = (const int*)d_in[3];
    const int* idx1   = (const int*)d_in[4];
    const int* idx2   = (const int*)d_in[5];
    int n = in_sizes[1];   // 8192
    int S = in_sizes[4];   // 5000

    // ws layout (all 8B-aligned by construction)
    char* p = (char*)d_ws;
    float* invn  = (float*)p;  p += (size_t)n * sizeof(float);        // n even
    int* bcnt    = (int*)p;    p += LMAX * sizeof(int);
    int* blist   = (int*)p;    p += (size_t)LMAX * MAXB * sizeof(int);
    int* paircnt = (int*)p;    p += sizeof(int);
    int* negcnt  = (int*)p;    p += sizeof(int);
    float* sums  = (float*)p;  p += 2 * sizeof(float);
    int2* pairs  = (int2*)p;   p += (size_t)PAIR_CAP * sizeof(int2);
    int2* negp   = (int2*)p;

    zero_kernel<<<1, 256, 0, stream>>>(bcnt, paircnt, negcnt, sums);

    int nb_prep = (n * 64 + 255) / 256;   // one wave per row
    prep_kernel<<<nb_prep, 256, 0, stream>>>(E, labels, cats, invn, bcnt, blist, n);

    int nb_pg = LMAX + (S + 255) / 256;
    pairgen_kernel<<<nb_pg, 256, 0, stream>>>(labels, graphs, cats, idx1, idx2, S,
                                              bcnt, blist, paircnt, pairs, negcnt, negp);

    dots_kernel<<<512, 256, 0, stream>>>(E, invn, pairs, paircnt, negp, negcnt, sums);

    finalize_kernel<<<1, 1, 0, stream>>>(sums, paircnt, negcnt, (float*)d_out);
}